// Round 7
// baseline (135.536 us; speedup 1.0000x reference)
//
#include <hip/hip_runtime.h>

// ConvT3d(32->16,k3,s2,p1)+BN+4^3 avgpool, bf16 MFMA.
// R12: 4 n-tiles/block pipeline (R11) + 3rd resident block restored.
// R11 cost a resident block (LDS 68.6KB -> 2/CU, occ 19%) and let VGPR grow
// to 128. Here: SINGLE xs buffer (19KB) -> LDS 48.7KB -> 3 blocks/CU;
// launch_bounds(256,3) (<=170 unified: acc 64 + F 36 + B 24 + misc ~155).
// Single buffer needs 2 barriers/tile: compute(t) -> bar (xs reads done,
// pbuf published) -> POOLW(t) (no parity-deferral; overlaps TRANSP) ->
// TRANSP(t+1) into same xs -> bar. Next tile's 9 float4 loads still issued
// BEFORE tile t's MFMAs (latency under compute). wT staged once per block
// via zero-VGPR global_load_lds (R10). Zero column (iw=32) written once;
// TRANSP only touches iw<32 so it survives all 4 tiles.
// Staging transpose (R8), parity decomposition (validated R1-R11):
//   even o: k=1,i=o/2; odd o=2m+1: k=0 -> i=m+1 ; k=2 -> i=m.
// kh-pair table: kh0: (hi1,oh1),(hi2,oh3); kh1: (hi0,oh0),(hi1,oh2);
//                kh2: (hi0,oh1),(hi1,oh3)

typedef __attribute__((ext_vector_type(8))) short bf16x8;
typedef __attribute__((ext_vector_type(4))) float f32x4;

static __device__ __forceinline__ unsigned short f2bf(float f) {
    unsigned int u = __float_as_uint(f);
    u = (u + 0x7fffu + ((u >> 16) & 1u)) >> 16;   // RNE
    return (unsigned short)u;
}
// RNE pack of 2 f32 -> 2 bf16 in one instr (identical rounding to f2bf)
static __device__ __forceinline__ unsigned cvtpk(float a, float b) {
    unsigned r;
    asm("v_cvt_pk_bf16_f32 %0, %1, %2" : "=v"(r) : "v"(a), "v"(b));
    return r;
}

// ---- w convert: w[ci][co][tap] fp32 -> wT[tap][co][ci] bf16 (tap=kd*9+kh*3+kw)
__global__ __launch_bounds__(256)
void kw(const float* __restrict__ w, unsigned short* __restrict__ wT)
{
    const int idx = blockIdx.x * 256 + threadIdx.x;
    if (idx < 13824) {
        const int ci = idx & 31, co = (idx >> 5) & 15, tap = idx >> 9;
        wT[idx] = f2bf(w[(ci * 16 + co) * 27 + tap]);
    }
}

// ---- fused stage + convT + BN-stats + pool partials, 4 n-tiles/block
__global__ __launch_bounds__(256, 3)
void convf2(const float* __restrict__ x,
            const unsigned short* __restrict__ wT,
            const float* __restrict__ bias,
            float* __restrict__ pooled,
            float* __restrict__ psum, float* __restrict__ psq)
{
    const int ht = blockIdx.x, dt = blockIdx.y, bz = blockIdx.z;
    const int n0 = bz * 4;
    const int tid = threadIdx.x;
    const int v = tid >> 6, lane = tid & 63;
    const int tw = v & 1, odp = v >> 1;         // ow 16-tile, od pair
    const int c = lane & 15, qd = lane >> 4;    // co / A-row m, K-granule

    // xs[dihi(9)][g(4)][iw(33)][o(8)] bf16 = 19008 B (single buffer)
    __shared__ alignas(16) unsigned short xs[9504];
    // wTs = linear copy of wT: [tap(27)][co(16)][ci(32)] bf16 = 27648 B
    __shared__ alignas(16) unsigned short wTs[13824];
    __shared__ float sred[4][16], qred[4][16], pbuf[2][8][16];

    const float bv = bias[c];

    // ---- stage wT -> LDS once per block, zero VGPR (27 x 1KB chunks)
    #pragma unroll
    for (int i = 0; i < 7; ++i) {
        const int chunk = v + 4 * i;            // wave-uniform
        if (chunk < 27) {
            __builtin_amdgcn_global_load_lds(
                (const char*)wT + chunk * 1024 + lane * 16,
                (char*)wTs + chunk * 1024,
                16, 0, 0);
        }
    }

    // ---- x staging geometry (block-uniform plane offsets/masks)
    const int ciS = tid >> 3, q = tid & 7;
    const int oL = ciS & 7;                     // = lane bits 3..5
    int  offp[9]; bool okp[9];
    #pragma unroll
    for (int p = 0; p < 9; ++p) {
        const int di = p / 3, hi = p - 3*(p/3);
        const int id = 2*dt + di, ih = 2*ht + hi;
        okp[p]  = (id < 32) && (ih < 32);
        offp[p] = id*1024 + ih*32;
    }
    float4 F[9];
    auto ISSUE = [&](int nn) {
        const float* xb = x + (size_t)(nn*32 + ciS)*32768 + 4*q;
        #pragma unroll
        for (int p = 0; p < 9; ++p)
            F[p] = okp[p] ? *(const float4*)(xb + offp[p])
                          : make_float4(0.f, 0.f, 0.f, 0.f);
    };
    // in-register transpose 4iw x 8ci -> [iw][o] packs (validated R8-R11)
    const unsigned selP = (lane & 8) ? 0x07060302u : 0x01000504u;
    const int iwT = 4*q + (oL & 3), hT = oL >> 2;
    auto TRANSP = [&]() {
        #pragma unroll
        for (int p = 0; p < 9; ++p) {
            unsigned u0 = cvtpk(F[p].x, F[p].y);
            unsigned u1 = cvtpk(F[p].z, F[p].w);
            const unsigned a0 = (unsigned)__shfl_xor((int)u0, 8, 64);
            const unsigned a1 = (unsigned)__shfl_xor((int)u1, 8, 64);
            u0 = __builtin_amdgcn_perm(u0, a0, selP);
            u1 = __builtin_amdgcn_perm(u1, a1, selP);
            const unsigned b0 = (unsigned)__shfl_xor((int)u0, 16, 64);
            const unsigned b1 = (unsigned)__shfl_xor((int)u1, 16, 64);
            const unsigned w0 = (lane & 16) ? b1 : u0;
            const unsigned w1 = (lane & 16) ? u1 : b0;
            *(uint2*)(xs + p*1056 + v*264 + iwT*8 + 4*hT) = make_uint2(w0, w1);
        }
    };

    // prologue: tile 0 staging + static zero column (iw=32, survives tiles)
    ISSUE(n0);
    if (tid < 36) {
        const int dihi = tid >> 2, gg = tid & 3;
        *(uint4*)(xs + dihi*1056 + gg*264 + 256) = make_uint4(0,0,0,0);
    }
    TRANSP();
    __syncthreads();   // drains vmcnt -> wTs + xs ready

    // kh-outer pair table: [kh][pair] -> (hi, oh)
    constexpr int KHP[3][2][2] = {
        {{1,1},{2,3}},   // kh0
        {{0,0},{1,2}},   // kh1
        {{0,1},{1,3}},   // kh2
    };
    const int PB[3]  = {9, 18, 0};       // tap base per phase (kd=1,2,0)
    const int POL[3] = {0, 1, 1};        // ol per phase
    const int PDI[3] = {odp, odp, odp + 1};
    const int iwb = 16 * tw + c;
    auto LDB = [&](int tap) -> bf16x8 {
        return *(const bf16x8*)(wTs + tap*512 + c*32 + qd*8);
    };
    auto LDA = [&](int dihi, int sofs) -> bf16x8 {
        return *(const bf16x8*)(xs + dihi*1056 + qd*264 + (iwb + sofs)*8);
    };
    const bool pok = (dt < 15) && (ht < 15);

    float sA = 0.f, sqA = 0.f;          // BN partials across 4 tiles

    for (int tt = 0; tt < 4; ++tt) {
        if (tt < 3) ISSUE(n0 + tt + 1);          // prefetch next tile's x

        f32x4 acc[2][4][2];   // [ol][oh][par]
        #pragma unroll
        for (int ol = 0; ol < 2; ++ol)
            #pragma unroll
            for (int oh = 0; oh < 4; ++oh)
                #pragma unroll
                for (int par = 0; par < 2; ++par)
                    acc[ol][oh][par] = (f32x4){0.f,0.f,0.f,0.f};

        bf16x8 B0 = LDB(9 + 0), B1 = LDB(9 + 1), B2 = LDB(9 + 2);
        #pragma unroll
        for (int s = 0; s < 9; ++s) {
            const int ph = s / 3;
            bf16x8 N0, N1, N2;
            if (s < 8) {                  // prefetch next kh-group (LDS)
                const int sn = s + 1;
                const int phn = sn / 3, khn = sn - 3*(sn/3);
                const int bn_ = PB[phn] + khn * 3;
                N0 = LDB(bn_ + 0); N1 = LDB(bn_ + 1); N2 = LDB(bn_ + 2);
            }
            const int kh = s - 3*(s/3);
            const int ol = POL[ph], di = PDI[ph];
            #pragma unroll
            for (int pp = 0; pp < 2; ++pp) {
                const int hi = KHP[kh][pp][0], oh = KHP[kh][pp][1];
                const bf16x8 A0 = LDA(di*3 + hi, 0), A1 = LDA(di*3 + hi, 1);
                acc[ol][oh][0] = __builtin_amdgcn_mfma_f32_16x16x32_bf16(
                    A0, B1, acc[ol][oh][0], 0, 0, 0);
                acc[ol][oh][1] = __builtin_amdgcn_mfma_f32_16x16x32_bf16(
                    A1, B0, acc[ol][oh][1], 0, 0, 0);
                acc[ol][oh][1] = __builtin_amdgcn_mfma_f32_16x16x32_bf16(
                    A0, B2, acc[ol][oh][1], 0, 0, 0);
            }
            if (s < 8) { B0 = N0; B1 = N1; B2 = N2; }
        }

        // epilogue: bias, BN stats (masked), pool partials (validated R2-R11)
        float P[2] = {0.f, 0.f};
        #pragma unroll
        for (int ol = 0; ol < 2; ++ol) {
            const int odg = 2*odp + ol;
            const bool odok = !(dt == 15 && odg == 3);
            #pragma unroll
            for (int oh = 0; oh < 4; ++oh) {
                const bool ohok = !(ht == 15 && oh == 3);
                #pragma unroll
                for (int par = 0; par < 2; ++par)
                    #pragma unroll
                    for (int r = 0; r < 4; ++r) {
                        const float val = acc[ol][oh][par][r] + bv;
                        const bool owok = !(par == 1 && tw == 1 && qd == 3 && r == 3);
                        const float mk = (odok && ohok && owok) ? 1.f : 0.f;
                        sA += mk * val; sqA += mk * val * val;
                        P[r >> 1] += val;
                    }
            }
        }
        if (odp == 0 && pok) {
            pbuf[tw][2*qd + 0][c] = P[0];
            pbuf[tw][2*qd + 1][c] = P[1];
        }

        __syncthreads();   // xs reads done, pbuf published

        if (odp == 1 && pok) {                   // pooled write (overlaps TRANSP)
            #pragma unroll
            for (int jj = 0; jj < 2; ++jj) {
                const int jl = 2*qd + jj, jg = 8*tw + jl;
                if (jg < 15) {
                    const float tot = pbuf[tw][jl][c] + P[jj];
                    pooled[((n0 + tt)*16 + c)*3375 + dt*225 + ht*15 + jg]
                        = tot * (1.f/64.f);
                }
            }
        }
        if (tt < 3) {
            TRANSP();                            // overwrite xs for next tile
            __syncthreads();                     // xs ready
        }
    }

    // single BN reduction for all 4 tiles
    sA  += __shfl_xor(sA, 16, 64);  sA  += __shfl_xor(sA, 32, 64);
    sqA += __shfl_xor(sqA, 16, 64); sqA += __shfl_xor(sqA, 32, 64);
    if (lane < 16) { sred[v][lane] = sA; qred[v][lane] = sqA; }
    __syncthreads();
    if (tid < 16) {
        const int blk = (bz*16 + dt)*16 + ht;    // [0,1024)
        psum[tid*4096 + blk] = sred[0][tid]+sred[1][tid]+sred[2][tid]+sred[3][tid];
        psq [tid*4096 + blk] = qred[0][tid]+qred[1][tid]+qred[2][tid]+qred[3][tid];
    }
}

__global__ void bnfinal(const float* __restrict__ psum, const float* __restrict__ psq,
                        const float* __restrict__ gamma, const float* __restrict__ beta,
                        float* __restrict__ bn)
{
    const int co = blockIdx.x;
    const int t  = threadIdx.x;
    float S = 0, Q = 0;
    for (int blk = t; blk < 1024; blk += 256) {
        S += psum[co*4096 + blk];
        Q += psq [co*4096 + blk];
    }
    #pragma unroll
    for (int off = 32; off > 0; off >>= 1) {
        S += __shfl_down(S, off, 64);
        Q += __shfl_down(Q, off, 64);
    }
    __shared__ float rs[4], rq[4];
    if ((t & 63) == 0) { rs[t >> 6] = S; rq[t >> 6] = Q; }
    __syncthreads();
    if (t == 0) {
        S = rs[0] + rs[1] + rs[2] + rs[3];
        Q = rq[0] + rq[1] + rq[2] + rq[3];
        const float cnt = 16.f * 63.f * 63.f * 63.f;
        const float mean = S / cnt;
        const float var  = Q / cnt - mean * mean;
        const float inv  = rsqrtf(var + 1e-5f);
        const float sc   = inv * gamma[co];
        bn[co]      = sc;
        bn[16 + co] = beta[co] - mean * sc;
    }
}

__global__ void finalize(const float* __restrict__ pooled, const float* __restrict__ bn,
                         float* __restrict__ out)
{
    const int i  = blockIdx.x * 256 + threadIdx.x;   // 864000 = 3375*256
    const int co = (i / 3375) & 15;
    out[i] = pooled[i] * bn[co] + bn[16 + co];
}

extern "C" void kernel_launch(void* const* d_in, const int* in_sizes, int n_in,
                              void* d_out, int out_size, void* d_ws, size_t ws_size,
                              hipStream_t stream)
{
    const float* x     = (const float*)d_in[0];
    const float* w     = (const float*)d_in[1];
    const float* b     = (const float*)d_in[2];
    const float* gamma = (const float*)d_in[3];
    const float* beta  = (const float*)d_in[4];
    float* out = (float*)d_out;

    char* wsb = (char*)d_ws;
    unsigned short* wT = (unsigned short*)wsb;        // 27,648 B
    float* pooled = (float*)(wsb + 27648);            // 3,456,000 B
    float* psum   = (float*)(wsb + 27648 + 3456000);  // 262,144 B
    float* psq    = (float*)(wsb + 27648 + 3456000 + 262144);
    float* bn     = (float*)(wsb + 27648 + 3456000 + 2*262144);

    kw<<<54, 256, 0, stream>>>(w, wT);
    dim3 grid(16, 16, 4);   // (ht, dt, n-quad)
    convf2<<<grid, 256, 0, stream>>>(x, wT, b, pooled, psum, psq);
    bnfinal<<<16, 256, 0, stream>>>(psum, psq, gamma, beta, bn);
    finalize<<<3375, 256, 0, stream>>>(pooled, bn, out);
}

// Round 8
// 134.602 us; speedup vs baseline: 1.0069x; 1.0069x over previous
//
#include <hip/hip_runtime.h>

// ConvT3d(32->16,k3,s2,p1)+BN+4^3 avgpool, bf16 MFMA.
// R13: 512-thr blocks, 1 od per wave -> half the per-thread resources,
// double the resident waves. Evidence R10-R12: ~190 total regs (128 arch +
// 64 AGPR acc) pinned us at 2 waves/SIMD (8 waves/CU) regardless of barrier
// structure; n-batching optimized inside that straitjacket. Now: 8 waves/
// block, wave odq in 0..3 owns ONE od (acc 64->32 AGPR), staging planes
// split over two 256-thr halves (F 36->20 VGPR), est total ~105 <= 128 ->
// launch_bounds(512,4) = 4 waves/SIMD = 16 waves/CU. Grid back to
// (16,16,16), one n per block; inter-block overlap hides staging (no
// pipeline needed). LDS = 19.0(xs) + 27.6(wTs) + 5.1(red+pbuf) = 51.8KB.
// Parity decomposition per wave (validated R1-R12): m = odq>>1;
//   even od=2m: kd=1, di=m (18 MFMA); odd od=2m+1: kd=2 di=m + kd=0 di=m+1.
// Pool: pbuf[4 odq][2 tw] partials, odq==3 waves sum 4 -> pooled
// (jg = 8tw+2qd+jj mapping unchanged; P[jj] sums par x r-pair = 4 ow).
// kh-pair table: kh0: (hi1,oh1),(hi2,oh3); kh1: (hi0,oh0),(hi1,oh2);
//                kh2: (hi0,oh1),(hi1,oh3)

typedef __attribute__((ext_vector_type(8))) short bf16x8;
typedef __attribute__((ext_vector_type(4))) float f32x4;

static __device__ __forceinline__ unsigned short f2bf(float f) {
    unsigned int u = __float_as_uint(f);
    u = (u + 0x7fffu + ((u >> 16) & 1u)) >> 16;   // RNE
    return (unsigned short)u;
}
// RNE pack of 2 f32 -> 2 bf16 in one instr (identical rounding to f2bf)
static __device__ __forceinline__ unsigned cvtpk(float a, float b) {
    unsigned r;
    asm("v_cvt_pk_bf16_f32 %0, %1, %2" : "=v"(r) : "v"(a), "v"(b));
    return r;
}

// ---- w convert: w[ci][co][tap] fp32 -> wT[tap][co][ci] bf16 (tap=kd*9+kh*3+kw)
__global__ __launch_bounds__(256)
void kw(const float* __restrict__ w, unsigned short* __restrict__ wT)
{
    const int idx = blockIdx.x * 256 + threadIdx.x;
    if (idx < 13824) {
        const int ci = idx & 31, co = (idx >> 5) & 15, tap = idx >> 9;
        wT[idx] = f2bf(w[(ci * 16 + co) * 27 + tap]);
    }
}

// ---- fused stage + convT + BN-stats + pool partials, 512 threads
__global__ __launch_bounds__(512, 4)
void convf2(const float* __restrict__ x,
            const unsigned short* __restrict__ wT,
            const float* __restrict__ bias,
            float* __restrict__ pooled,
            float* __restrict__ psum, float* __restrict__ psq)
{
    const int ht = blockIdx.x, dt = blockIdx.y, n = blockIdx.z;
    const int tid = threadIdx.x;
    const int vv = tid >> 6, lane = tid & 63;   // wave 0..7
    const int tw = vv & 1, odq = vv >> 1;       // ow half / od index
    const int c = lane & 15, qd = lane >> 4;    // co / K-granule

    // xs[dihi(9)][g(4)][iw(33)][o(8)] bf16 = 19008 B
    __shared__ alignas(16) unsigned short xs[9504];
    // wTs = linear copy of wT: [tap(27)][co(16)][ci(32)] bf16 = 27648 B
    __shared__ alignas(16) unsigned short wTs[13824];
    __shared__ float sred[8][16], qred[8][16], pbuf[4][2][8][16];

    const float bv = bias[c];

    // ---- stage wT -> LDS, zero VGPR (27 x 1KB chunks over 8 waves)
    #pragma unroll
    for (int i = 0; i < 4; ++i) {
        const int chunk = vv + 8 * i;           // wave-uniform
        if (chunk < 27) {
            __builtin_amdgcn_global_load_lds(
                (const char*)wT + chunk * 1024 + lane * 16,
                (char*)wTs + chunk * 1024,
                16, 0, 0);
        }
    }

    // ---- stage x: half h = tid>>8 covers planes p = 2i+h (5 / 4 planes)
    const int h = tid >> 8, ltid = tid & 255;
    const int ciS = ltid >> 3, q = ltid & 7;
    const int oL = ciS & 7;                     // = lane bits 3..5
    const int g = ciS >> 3;                     // ci-octet = vv&3
    const float* xbase = x + (size_t)(n*32 + ciS)*32768 + 4*q;
    float4 F[5];
    #pragma unroll
    for (int i = 0; i < 5; ++i) {
        const int p = 2*i + h;
        if (p < 9) {
            const int di = p / 3, hp = p - 3*(p/3);
            const int id = 2*dt + di, ih = 2*ht + hp;
            F[i] = (id < 32 && ih < 32)
                 ? *(const float4*)(xbase + id*1024 + ih*32)
                 : make_float4(0.f, 0.f, 0.f, 0.f);
        }
    }
    // in-register transpose 4iw x 8ci -> [iw][o] packs (validated R8-R12)
    const unsigned selP = (lane & 8) ? 0x07060302u : 0x01000504u;
    const int iwT = 4*q + (oL & 3), hT = oL >> 2;
    #pragma unroll
    for (int i = 0; i < 5; ++i) {
        const int p = 2*i + h;
        if (p < 9) {
            unsigned u0 = cvtpk(F[i].x, F[i].y);
            unsigned u1 = cvtpk(F[i].z, F[i].w);
            const unsigned a0 = (unsigned)__shfl_xor((int)u0, 8, 64);
            const unsigned a1 = (unsigned)__shfl_xor((int)u1, 8, 64);
            u0 = __builtin_amdgcn_perm(u0, a0, selP);
            u1 = __builtin_amdgcn_perm(u1, a1, selP);
            const unsigned s0 = (unsigned)__shfl_xor((int)u0, 16, 64);
            const unsigned s1 = (unsigned)__shfl_xor((int)u1, 16, 64);
            const unsigned w0 = (lane & 16) ? s1 : u0;
            const unsigned w1 = (lane & 16) ? u1 : s0;
            *(uint2*)(xs + p*1056 + g*264 + iwT*8 + 4*hT) = make_uint2(w0, w1);
        }
    }
    if (tid < 36) {
        const int dihi = tid >> 2, gg = tid & 3;
        *(uint4*)(xs + dihi*1056 + gg*264 + 256) = make_uint4(0,0,0,0);
    }

    __syncthreads();   // drains vmcnt -> wTs + xs ready

    // ---- compute: wave owns od = odq
    f32x4 acc[4][2];   // [oh][par]
    #pragma unroll
    for (int oh = 0; oh < 4; ++oh)
        #pragma unroll
        for (int par = 0; par < 2; ++par)
            acc[oh][par] = (f32x4){0.f,0.f,0.f,0.f};

    const int iwb = 16 * tw + c;
    auto LDA = [&](int dihi, int sofs) -> bf16x8 {
        return *(const bf16x8*)(xs + dihi*1056 + qd*264 + (iwb + sofs)*8);
    };
    auto LDB = [&](int tap) -> bf16x8 {
        return *(const bf16x8*)(wTs + tap*512 + c*32 + qd*8);
    };
    constexpr int KHP[3][2][2] = {
        {{1,1},{2,3}},   // kh0
        {{0,0},{1,2}},   // kh1
        {{0,1},{1,3}},   // kh2
    };
    auto PH = [&](int base, int di) {
        #pragma unroll
        for (int kh = 0; kh < 3; ++kh) {
            const bf16x8 B0 = LDB(base + kh*3 + 0);
            const bf16x8 B1 = LDB(base + kh*3 + 1);
            const bf16x8 B2 = LDB(base + kh*3 + 2);
            #pragma unroll
            for (int pp = 0; pp < 2; ++pp) {
                const int hi = KHP[kh][pp][0], oh = KHP[kh][pp][1];
                const bf16x8 A0 = LDA(di*3 + hi, 0), A1 = LDA(di*3 + hi, 1);
                acc[oh][0] = __builtin_amdgcn_mfma_f32_16x16x32_bf16(
                    A0, B1, acc[oh][0], 0, 0, 0);
                acc[oh][1] = __builtin_amdgcn_mfma_f32_16x16x32_bf16(
                    A1, B0, acc[oh][1], 0, 0, 0);
                acc[oh][1] = __builtin_amdgcn_mfma_f32_16x16x32_bf16(
                    A0, B2, acc[oh][1], 0, 0, 0);
            }
        }
    };
    const int m = odq >> 1;
    if ((odq & 1) == 0) {
        PH(9, m);                 // even od=2m: kd=1, di=m
    } else {
        PH(18, m);                // odd od=2m+1: kd=2, di=m
        PH(0,  m + 1);            //              kd=0, di=m+1
    }

    // ---- epilogue: bias, BN stats (masked), pool partials
    float sA = 0.f, sqA = 0.f;
    float P[2] = {0.f, 0.f};
    const bool odok = !(dt == 15 && odq == 3);
    #pragma unroll
    for (int oh = 0; oh < 4; ++oh) {
        const bool ohok = !(ht == 15 && oh == 3);
        #pragma unroll
        for (int par = 0; par < 2; ++par)
            #pragma unroll
            for (int r = 0; r < 4; ++r) {
                const float val = acc[oh][par][r] + bv;
                const bool owok = !(par == 1 && tw == 1 && qd == 3 && r == 3);
                const float mk = (odok && ohok && owok) ? 1.f : 0.f;
                sA += mk * val; sqA += mk * val * val;
                P[r >> 1] += val;
            }
    }
    sA  += __shfl_xor(sA, 16, 64);  sA  += __shfl_xor(sA, 32, 64);
    sqA += __shfl_xor(sqA, 16, 64); sqA += __shfl_xor(sqA, 32, 64);
    if (lane < 16) { sred[vv][lane] = sA; qred[vv][lane] = sqA; }
    pbuf[odq][tw][2*qd + 0][c] = P[0];
    pbuf[odq][tw][2*qd + 1][c] = P[1];

    __syncthreads();

    if (tid < 16) {
        const int blk = (n*16 + dt)*16 + ht;     // [0,4096)
        float S = 0.f, Q = 0.f;
        #pragma unroll
        for (int wv = 0; wv < 8; ++wv) { S += sred[wv][tid]; Q += qred[wv][tid]; }
        psum[tid*4096 + blk] = S;
        psq [tid*4096 + blk] = Q;
    }
    if (odq == 3 && dt < 15 && ht < 15) {        // pool: sum 4 od partials
        #pragma unroll
        for (int jj = 0; jj < 2; ++jj) {
            const int jl = 2*qd + jj, jg = 8*tw + jl;
            if (jg < 15) {
                const float tot = pbuf[0][tw][jl][c] + pbuf[1][tw][jl][c]
                                + pbuf[2][tw][jl][c] + pbuf[3][tw][jl][c];
                pooled[(n*16 + c)*3375 + dt*225 + ht*15 + jg] = tot * (1.f/64.f);
            }
        }
    }
}

__global__ void bnfinal(const float* __restrict__ psum, const float* __restrict__ psq,
                        const float* __restrict__ gamma, const float* __restrict__ beta,
                        float* __restrict__ bn)
{
    const int co = blockIdx.x;
    const int t  = threadIdx.x;
    float S = 0, Q = 0;
    for (int blk = t; blk < 4096; blk += 256) {
        S += psum[co*4096 + blk];
        Q += psq [co*4096 + blk];
    }
    #pragma unroll
    for (int off = 32; off > 0; off >>= 1) {
        S += __shfl_down(S, off, 64);
        Q += __shfl_down(Q, off, 64);
    }
    __shared__ float rs[4], rq[4];
    if ((t & 63) == 0) { rs[t >> 6] = S; rq[t >> 6] = Q; }
    __syncthreads();
    if (t == 0) {
        S = rs[0] + rs[1] + rs[2] + rs[3];
        Q = rq[0] + rq[1] + rq[2] + rq[3];
        const float cnt = 16.f * 63.f * 63.f * 63.f;
        const float mean = S / cnt;
        const float var  = Q / cnt - mean * mean;
        const float inv  = rsqrtf(var + 1e-5f);
        const float sc   = inv * gamma[co];
        bn[co]      = sc;
        bn[16 + co] = beta[co] - mean * sc;
    }
}

__global__ void finalize(const float* __restrict__ pooled, const float* __restrict__ bn,
                         float* __restrict__ out)
{
    const int i  = blockIdx.x * 256 + threadIdx.x;   // 864000 = 3375*256
    const int co = (i / 3375) & 15;
    out[i] = pooled[i] * bn[co] + bn[16 + co];
}

extern "C" void kernel_launch(void* const* d_in, const int* in_sizes, int n_in,
                              void* d_out, int out_size, void* d_ws, size_t ws_size,
                              hipStream_t stream)
{
    const float* x     = (const float*)d_in[0];
    const float* w     = (const float*)d_in[1];
    const float* b     = (const float*)d_in[2];
    const float* gamma = (const float*)d_in[3];
    const float* beta  = (const float*)d_in[4];
    float* out = (float*)d_out;

    char* wsb = (char*)d_ws;
    unsigned short* wT = (unsigned short*)wsb;        // 27,648 B
    float* pooled = (float*)(wsb + 27648);            // 3,456,000 B
    float* psum   = (float*)(wsb + 27648 + 3456000);  // 262,144 B
    float* psq    = (float*)(wsb + 27648 + 3456000 + 262144);
    float* bn     = (float*)(wsb + 27648 + 3456000 + 2*262144);

    kw<<<54, 256, 0, stream>>>(w, wT);
    dim3 grid(16, 16, 16);   // (ht, dt, n)
    convf2<<<grid, 512, 0, stream>>>(x, wT, b, pooled, psum, psq);
    bnfinal<<<16, 256, 0, stream>>>(psum, psq, gamma, beta, bn);
    finalize<<<3375, 256, 0, stream>>>(pooled, bn, out);
}

// Round 9
// 128.948 us; speedup vs baseline: 1.0511x; 1.0438x over previous
//
#include <hip/hip_runtime.h>

// ConvT3d(32->16,k3,s2,p1)+BN+4^3 avgpool, bf16 MFMA.
// R14: VALU cut + 3rd resident block. R13 counters: VALUBusy 43% @45.5us =
// ~20us of VALU issue -> the epilogue (~200 ops/thread: per-element mk masks
// + bias adds + P adds over 32 acc elems) is now the largest consumer.
// Changes:
//  1) bias folded OUT of the hot loop. Epilogue works on RAW acc; biased BN
//     sums via closed form: s = s_raw + cnt*bv ; sq = sq_raw + 2bv*s_raw +
//     cnt*bv^2. pooled stores RAW conv mean; bias enters bnfinal's affine
//     offset: out = praw*sc + (beta + (bias-mean)*sc).
//  2) block-uniform fast path (dt<15 && ht<15, 225/256 blocks): no masks,
//     2 ops/elem (P add + sq fma); ow63 removed by predicated 8-op corr on
//     tw1/qd3 threads; cnt = 28/32. Edge blocks keep masked path (raw acc).
//  3) launch_bounds(512,6): LDS 51.8KB -> 3 blocks/CU (155KB), reg cap ~85
//     (arch 44 + acc 32 = 76 fits) -> up to 24 waves/CU. Spill tripwire:
//     WRITE_SIZE ballooning (R9 mode).
// R13 structure otherwise: 512 thr, wave odq owns one od, m=odq>>1;
//   even od=2m: kd=1 di=m; odd od=2m+1: kd=2 di=m + kd=0 di=m+1.
// wT staged once/block via zero-VGPR global_load_lds (R10); x via 9(5/4)
// float4 + in-reg transpose (R8). Parity decomposition validated R1-R13.
// kh-pair: kh0:(hi1,oh1),(hi2,oh3); kh1:(hi0,oh0),(hi1,oh2);
//          kh2:(hi0,oh1),(hi1,oh3)

typedef __attribute__((ext_vector_type(8))) short bf16x8;
typedef __attribute__((ext_vector_type(4))) float f32x4;

static __device__ __forceinline__ unsigned short f2bf(float f) {
    unsigned int u = __float_as_uint(f);
    u = (u + 0x7fffu + ((u >> 16) & 1u)) >> 16;   // RNE
    return (unsigned short)u;
}
static __device__ __forceinline__ unsigned cvtpk(float a, float b) {
    unsigned r;
    asm("v_cvt_pk_bf16_f32 %0, %1, %2" : "=v"(r) : "v"(a), "v"(b));
    return r;
}

// ---- w convert: w[ci][co][tap] fp32 -> wT[tap][co][ci] bf16 (tap=kd*9+kh*3+kw)
__global__ __launch_bounds__(256)
void kw(const float* __restrict__ w, unsigned short* __restrict__ wT)
{
    const int idx = blockIdx.x * 256 + threadIdx.x;
    if (idx < 13824) {
        const int ci = idx & 31, co = (idx >> 5) & 15, tap = idx >> 9;
        wT[idx] = f2bf(w[(ci * 16 + co) * 27 + tap]);
    }
}

// ---- fused stage + convT + BN-stats + pool partials, 512 threads
__global__ __launch_bounds__(512, 6)
void convf2(const float* __restrict__ x,
            const unsigned short* __restrict__ wT,
            const float* __restrict__ bias,
            float* __restrict__ pooled,
            float* __restrict__ psum, float* __restrict__ psq)
{
    const int ht = blockIdx.x, dt = blockIdx.y, n = blockIdx.z;
    const int tid = threadIdx.x;
    const int vv = tid >> 6, lane = tid & 63;   // wave 0..7
    const int tw = vv & 1, odq = vv >> 1;       // ow half / od index
    const int c = lane & 15, qd = lane >> 4;    // co / K-granule

    __shared__ alignas(16) unsigned short xs[9504];    // 19008 B
    __shared__ alignas(16) unsigned short wTs[13824];  // 27648 B
    __shared__ float sred[8][16], qred[8][16], pbuf[4][2][8][16];

    const float bv = bias[c];                   // one 4B load, L1-resident

    // ---- stage wT -> LDS, zero VGPR (27 x 1KB chunks over 8 waves)
    #pragma unroll
    for (int i = 0; i < 4; ++i) {
        const int chunk = vv + 8 * i;           // wave-uniform
        if (chunk < 27) {
            __builtin_amdgcn_global_load_lds(
                (const char*)wT + chunk * 1024 + lane * 16,
                (char*)wTs + chunk * 1024,
                16, 0, 0);
        }
    }

    // ---- stage x: half h = tid>>8 covers planes p = 2i+h (5 / 4 planes)
    const int h = tid >> 8, ltid = tid & 255;
    const int ciS = ltid >> 3, q = ltid & 7;
    const int oL = ciS & 7;
    const int g = ciS >> 3;
    const float* xbase = x + (size_t)(n*32 + ciS)*32768 + 4*q;
    float4 F[5];
    #pragma unroll
    for (int i = 0; i < 5; ++i) {
        const int p = 2*i + h;
        if (p < 9) {
            const int di = p / 3, hp = p - 3*(p/3);
            const int id = 2*dt + di, ih = 2*ht + hp;
            F[i] = (id < 32 && ih < 32)
                 ? *(const float4*)(xbase + id*1024 + ih*32)
                 : make_float4(0.f, 0.f, 0.f, 0.f);
        }
    }
    const unsigned selP = (lane & 8) ? 0x07060302u : 0x01000504u;
    const int iwT = 4*q + (oL & 3), hT = oL >> 2;
    #pragma unroll
    for (int i = 0; i < 5; ++i) {
        const int p = 2*i + h;
        if (p < 9) {
            unsigned u0 = cvtpk(F[i].x, F[i].y);
            unsigned u1 = cvtpk(F[i].z, F[i].w);
            const unsigned a0 = (unsigned)__shfl_xor((int)u0, 8, 64);
            const unsigned a1 = (unsigned)__shfl_xor((int)u1, 8, 64);
            u0 = __builtin_amdgcn_perm(u0, a0, selP);
            u1 = __builtin_amdgcn_perm(u1, a1, selP);
            const unsigned s0 = (unsigned)__shfl_xor((int)u0, 16, 64);
            const unsigned s1 = (unsigned)__shfl_xor((int)u1, 16, 64);
            const unsigned w0 = (lane & 16) ? s1 : u0;
            const unsigned w1 = (lane & 16) ? u1 : s0;
            *(uint2*)(xs + p*1056 + g*264 + iwT*8 + 4*hT) = make_uint2(w0, w1);
        }
    }
    if (tid < 36) {
        const int dihi = tid >> 2, gg = tid & 3;
        *(uint4*)(xs + dihi*1056 + gg*264 + 256) = make_uint4(0,0,0,0);
    }

    __syncthreads();   // drains vmcnt -> wTs + xs ready

    // ---- compute: wave owns od = odq
    f32x4 acc[4][2];   // [oh][par]
    #pragma unroll
    for (int oh = 0; oh < 4; ++oh)
        #pragma unroll
        for (int par = 0; par < 2; ++par)
            acc[oh][par] = (f32x4){0.f,0.f,0.f,0.f};

    const int iwb = 16 * tw + c;
    auto LDA = [&](int dihi, int sofs) -> bf16x8 {
        return *(const bf16x8*)(xs + dihi*1056 + qd*264 + (iwb + sofs)*8);
    };
    auto LDB = [&](int tap) -> bf16x8 {
        return *(const bf16x8*)(wTs + tap*512 + c*32 + qd*8);
    };
    constexpr int KHP[3][2][2] = {
        {{1,1},{2,3}},   // kh0
        {{0,0},{1,2}},   // kh1
        {{0,1},{1,3}},   // kh2
    };
    auto PH = [&](int base, int di) {
        #pragma unroll
        for (int kh = 0; kh < 3; ++kh) {
            const bf16x8 B0 = LDB(base + kh*3 + 0);
            const bf16x8 B1 = LDB(base + kh*3 + 1);
            const bf16x8 B2 = LDB(base + kh*3 + 2);
            #pragma unroll
            for (int pp = 0; pp < 2; ++pp) {
                const int hi = KHP[kh][pp][0], oh = KHP[kh][pp][1];
                const bf16x8 A0 = LDA(di*3 + hi, 0), A1 = LDA(di*3 + hi, 1);
                acc[oh][0] = __builtin_amdgcn_mfma_f32_16x16x32_bf16(
                    A0, B1, acc[oh][0], 0, 0, 0);
                acc[oh][1] = __builtin_amdgcn_mfma_f32_16x16x32_bf16(
                    A1, B0, acc[oh][1], 0, 0, 0);
                acc[oh][1] = __builtin_amdgcn_mfma_f32_16x16x32_bf16(
                    A0, B2, acc[oh][1], 0, 0, 0);
            }
        }
    };
    const int m = odq >> 1;
    if ((odq & 1) == 0) {
        PH(9, m);                 // even od=2m: kd=1, di=m
    } else {
        PH(18, m);                // odd od=2m+1: kd=2, di=m
        PH(0,  m + 1);            //              kd=0, di=m+1
    }

    // ---- epilogue on RAW acc
    const bool inter = (dt < 15) && (ht < 15);
    const bool owx = (tw == 1) && (qd == 3);    // this thread holds ow==63
    float s_raw, sq_raw, cnt;
    float P0 = 0.f, P1 = 0.f;
    if (inter) {
        float sqr = 0.f;
        #pragma unroll
        for (int oh = 0; oh < 4; ++oh)
            #pragma unroll
            for (int par = 0; par < 2; ++par) {
                const f32x4 a = acc[oh][par];
                P0 += a[0]; sqr = fmaf(a[0], a[0], sqr);
                P0 += a[1]; sqr = fmaf(a[1], a[1], sqr);
                P1 += a[2]; sqr = fmaf(a[2], a[2], sqr);
                P1 += a[3]; sqr = fmaf(a[3], a[3], sqr);
            }
        float corr = 0.f, corrq = 0.f;
        if (owx) {                               // remove ow==63 (par1,r3)
            #pragma unroll
            for (int oh = 0; oh < 4; ++oh) {
                const float a = acc[oh][1][3];
                corr += a; corrq = fmaf(a, a, corrq);
            }
        }
        s_raw  = (P0 + P1) - corr;
        sq_raw = sqr - corrq;
        cnt    = owx ? 28.f : 32.f;
    } else {
        s_raw = 0.f; sq_raw = 0.f; cnt = 0.f;
        const bool odok = !(dt == 15 && odq == 3);
        #pragma unroll
        for (int oh = 0; oh < 4; ++oh) {
            const bool ohok = !(ht == 15 && oh == 3);
            #pragma unroll
            for (int par = 0; par < 2; ++par)
                #pragma unroll
                for (int r = 0; r < 4; ++r) {
                    const float a = acc[oh][par][r];
                    const bool owok = !(par == 1 && owx && r == 3);
                    const float mk = (odok && ohok && owok) ? 1.f : 0.f;
                    const float t = mk * a;
                    s_raw += t; sq_raw = fmaf(t, a, sq_raw); cnt += mk;
                }
        }
    }
    // biased sums via closed form
    float s_b  = fmaf(cnt, bv, s_raw);
    float sq_b = fmaf(fmaf(cnt, bv, 2.f * s_raw), bv, sq_raw);

    s_b  += __shfl_xor(s_b, 16, 64);  s_b  += __shfl_xor(s_b, 32, 64);
    sq_b += __shfl_xor(sq_b, 16, 64); sq_b += __shfl_xor(sq_b, 32, 64);
    if (lane < 16) { sred[vv][lane] = s_b; qred[vv][lane] = sq_b; }
    pbuf[odq][tw][2*qd + 0][c] = P0;
    pbuf[odq][tw][2*qd + 1][c] = P1;

    __syncthreads();

    if (tid < 16) {
        const int blk = (n*16 + dt)*16 + ht;
        float S = 0.f, Q = 0.f;
        #pragma unroll
        for (int wv = 0; wv < 8; ++wv) { S += sred[wv][tid]; Q += qred[wv][tid]; }
        psum[tid*4096 + blk] = S;
        psq [tid*4096 + blk] = Q;
    }
    if (odq == 3 && inter) {                     // pool: sum 4 od partials (RAW)
        #pragma unroll
        for (int jj = 0; jj < 2; ++jj) {
            const int jl = 2*qd + jj, jg = 8*tw + jl;
            if (jg < 15) {
                const float tot = pbuf[0][tw][jl][c] + pbuf[1][tw][jl][c]
                                + pbuf[2][tw][jl][c] + pbuf[3][tw][jl][c];
                pooled[(n*16 + c)*3375 + dt*225 + ht*15 + jg] = tot * (1.f/64.f);
            }
        }
    }
}

__global__ void bnfinal(const float* __restrict__ psum, const float* __restrict__ psq,
                        const float* __restrict__ gamma, const float* __restrict__ beta,
                        const float* __restrict__ bias,
                        float* __restrict__ bn)
{
    const int co = blockIdx.x;
    const int t  = threadIdx.x;
    float S = 0, Q = 0;
    for (int blk = t; blk < 4096; blk += 256) {
        S += psum[co*4096 + blk];
        Q += psq [co*4096 + blk];
    }
    #pragma unroll
    for (int off = 32; off > 0; off >>= 1) {
        S += __shfl_down(S, off, 64);
        Q += __shfl_down(Q, off, 64);
    }
    __shared__ float rs[4], rq[4];
    if ((t & 63) == 0) { rs[t >> 6] = S; rq[t >> 6] = Q; }
    __syncthreads();
    if (t == 0) {
        S = rs[0] + rs[1] + rs[2] + rs[3];
        Q = rq[0] + rq[1] + rq[2] + rq[3];
        const float cnt = 16.f * 63.f * 63.f * 63.f;
        const float mean = S / cnt;
        const float var  = Q / cnt - mean * mean;
        const float inv  = rsqrtf(var + 1e-5f);
        const float sc   = inv * gamma[co];
        bn[co]      = sc;
        // pooled stores RAW conv mean; bias enters the affine offset
        bn[16 + co] = beta[co] + (bias[co] - mean) * sc;
    }
}

__global__ void finalize(const float* __restrict__ pooled, const float* __restrict__ bn,
                         float* __restrict__ out)
{
    const int i  = blockIdx.x * 256 + threadIdx.x;   // 864000 = 3375*256
    const int co = (i / 3375) & 15;
    out[i] = pooled[i] * bn[co] + bn[16 + co];
}

extern "C" void kernel_launch(void* const* d_in, const int* in_sizes, int n_in,
                              void* d_out, int out_size, void* d_ws, size_t ws_size,
                              hipStream_t stream)
{
    const float* x     = (const float*)d_in[0];
    const float* w     = (const float*)d_in[1];
    const float* b     = (const float*)d_in[2];
    const float* gamma = (const float*)d_in[3];
    const float* beta  = (const float*)d_in[4];
    float* out = (float*)d_out;

    char* wsb = (char*)d_ws;
    unsigned short* wT = (unsigned short*)wsb;        // 27,648 B
    float* pooled = (float*)(wsb + 27648);            // 3,456,000 B
    float* psum   = (float*)(wsb + 27648 + 3456000);  // 262,144 B
    float* psq    = (float*)(wsb + 27648 + 3456000 + 262144);
    float* bn     = (float*)(wsb + 27648 + 3456000 + 2*262144);

    kw<<<54, 256, 0, stream>>>(w, wT);
    dim3 grid(16, 16, 16);   // (ht, dt, n)
    convf2<<<grid, 512, 0, stream>>>(x, wT, b, pooled, psum, psq);
    bnfinal<<<16, 256, 0, stream>>>(psum, psq, gamma, beta, b, bn);
    finalize<<<3375, 256, 0, stream>>>(pooled, bn, out);
}